// Round 10
// baseline (777.144 us; speedup 1.0000x reference)
//
#include <hip/hip_runtime.h>

// SensorAutoEncoder: 10-layer MLP over 1M rows of 43 floats, fused persistent
// kernel. fp16 MFMA (16x16x32) + fp32 accumulate. R10 = R9's math with the
// occupancy unlock: per-wave M = 16 rows (no s-loop), x lives in registers
// (4x f32x4, prefetched), LDS = weights only (64,000 B) -> 2 blocks/CU
// -> 8 waves/SIMD (was 4). Register-resident layer chain unchanged:
//   B slot (c,g,j): c==0 -> F = 16*(j>>2) + 4g + (j&3)
//                   c==1, j<4 -> F = 32 + 4g + j ; else zero pad
// k-permutation F folded into weight staging; bias via k==KL row; forced 1.0
// multiplier at slot (c1,g=1,j=3); junk k-slots annihilated by zero A rows.

typedef __fp16 pk16x2 __attribute__((ext_vector_type(2)));   // cvt_pkrtz type
typedef _Float16 f16x8 __attribute__((ext_vector_type(8)));
typedef float f32x4 __attribute__((ext_vector_type(4)));
typedef unsigned u32x4 __attribute__((ext_vector_type(4)));

#define TPB 1024
#define NBLK 512
#define ITERS 8
#define NROWS 1048576
#define NCOL 43
#define ROWB 172u                        // bytes per x / out row (43 f32)
#define XBYTES ((size_t)NROWS * ROWB)    // 180,355,072
#define WSTRIDE 72                       // halfwords per W^T row (144 B)
#define SLOT_ROWS 44
#define WSLOT (SLOT_ROWS * WSTRIDE)      // 3168 halfwords per layer slot
#define W_BYTES (10 * WSLOT * 2)         // 63360 B
#define W_PAD 640                        // layer-9 A-read overhang (rows 44..47)
#define SMEM_BYTES (W_BYTES + W_PAD)     // 64000 B -> 2 blocks/CU fits 160 KiB

__device__ __forceinline__ float fast_tanh(float x) {
  // tanh(x) = 1 - 2/(1 + e^{2x});  e^{2x} = 2^{x * 2*log2(e)}
  float t = __builtin_amdgcn_exp2f(x * 2.8853900817779268f);
  float r = __builtin_amdgcn_rcpf(t + 1.0f);
  return __builtin_fmaf(-2.0f, r, 1.0f);
}

__device__ __forceinline__ unsigned pk2(float a, float b) {
  pk16x2 h = __builtin_amdgcn_cvt_pkrtz(a, b);
  return __builtin_bit_cast(unsigned, h);
}

struct Frag2 { f16x8 c0, c1; };

// One layer: JIT A-reads from LDS weights, MFMA (zero-C first chunk),
// epilogue (tanh + bias-column 1.0 forcing), pack into next B-frag.
template <int NT, int KC, bool DOTANH, int NLOUT, int KCN>
__device__ __forceinline__ Frag2 layer_fwd(const _Float16* __restrict__ Wl,
                                           Frag2 Bi, f32x4 Z, int g, int lr) {
  const _Float16* p = Wl + lr * WSTRIDE + 8 * g;
  f32x4 acc[3];
  acc[0] = __builtin_amdgcn_mfma_f32_16x16x32_f16(*(const f16x8*)(p),
                                                  Bi.c0, Z, 0, 0, 0);
  if constexpr (NT > 1)
    acc[1] = __builtin_amdgcn_mfma_f32_16x16x32_f16(
        *(const f16x8*)(p + 16 * WSTRIDE), Bi.c0, Z, 0, 0, 0);
  if constexpr (NT > 2)
    acc[2] = __builtin_amdgcn_mfma_f32_16x16x32_f16(
        *(const f16x8*)(p + 32 * WSTRIDE), Bi.c0, Z, 0, 0, 0);
  if constexpr (KC > 1) {
    acc[0] = __builtin_amdgcn_mfma_f32_16x16x32_f16(*(const f16x8*)(p + 32),
                                                    Bi.c1, acc[0], 0, 0, 0);
    if constexpr (NT > 1)
      acc[1] = __builtin_amdgcn_mfma_f32_16x16x32_f16(
          *(const f16x8*)(p + 16 * WSTRIDE + 32), Bi.c1, acc[1], 0, 0, 0);
    if constexpr (NT > 2)
      acc[2] = __builtin_amdgcn_mfma_f32_16x16x32_f16(
          *(const f16x8*)(p + 32 * WSTRIDE + 32), Bi.c1, acc[2], 0, 0, 0);
  }

  unsigned pk[3][2];
#pragma unroll
  for (int t = 0; t < NT; ++t) {
    float v[4];
#pragma unroll
    for (int r = 0; r < 4; ++r) {
      float u = acc[t][r];
      if (DOTANH) u = fast_tanh(u);
      if (t == (NLOUT >> 4)) {                 // bias-mult column -> 1.0
        int col = 16 * t + 4 * g + r;
        u = (col == NLOUT) ? 1.0f : u;
      }
      v[r] = u;
    }
    pk[t][0] = pk2(v[0], v[1]);
    pk[t][1] = pk2(v[2], v[3]);
  }
  Frag2 O;
  u32x4 d0 = {pk[0][0], pk[0][1], pk[1][0], pk[1][1]};
  O.c0 = __builtin_bit_cast(f16x8, d0);
  if (KCN == 2) {
    u32x4 d1 = {pk[NT - 1][0], pk[NT - 1][1], 0u, 0u};
    O.c1 = __builtin_bit_cast(f16x8, d1);
  } else {
    O.c1 = O.c0;   // unused by a KC=1 consumer
  }
  return O;
}

extern "C" __global__ void __launch_bounds__(TPB, 8)
ae_kernel(const float* __restrict__ x,
          const float* __restrict__ W0, const float* __restrict__ B0,
          const float* __restrict__ W1, const float* __restrict__ B1,
          const float* __restrict__ W2, const float* __restrict__ B2,
          const float* __restrict__ W3, const float* __restrict__ B3,
          const float* __restrict__ W4, const float* __restrict__ B4,
          const float* __restrict__ W5, const float* __restrict__ B5,
          const float* __restrict__ W6, const float* __restrict__ B6,
          const float* __restrict__ W7, const float* __restrict__ B7,
          const float* __restrict__ W8, const float* __restrict__ B8,
          const float* __restrict__ W9, const float* __restrict__ B9,
          float* __restrict__ out) {
  extern __shared__ char smem[];
  _Float16* lw = (_Float16*)smem;

  const int tid = threadIdx.x;
  const int wave = tid >> 6;
  const int lane = tid & 63;
  const int g = lane >> 4;
  const int lr = lane & 15;

  // ---- stage weights as fp16 W^T (k-permutation F for layers 1..9), bias
  //      at the slot mapping to k==KL; 44 rows per slot ----
  {
    const float* Wp[10] = {W0, W1, W2, W3, W4, W5, W6, W7, W8, W9};
    const float* Bp[10] = {B0, B1, B2, B3, B4, B5, B6, B7, B8, B9};
    const int KLs[10] = {43, 43, 43, 43, 43, 21, 43, 43, 43, 43};
    const int NLs[10] = {43, 43, 43, 43, 21, 43, 43, 43, 43, 43};
#pragma unroll
    for (int L = 0; L < 10; ++L) {
      const float* Wl = Wp[L];
      const float* Bl = Bp[L];
      const int KL = KLs[L], NL = NLs[L];
      for (int idx = tid; idx < SLOT_ROWS * 64; idx += TPB) {
        int n = idx >> 6, kp = idx & 63;
        float v = 0.0f;
        if (n < NL) {
          int c = kp >> 5, g2 = (kp >> 3) & 3, j = kp & 7;
          int F;
          if (L == 0) F = kp;                               // natural
          else if (c == 0) F = 16 * (j >> 2) + 4 * g2 + (j & 3);
          else if (j < 4)  F = 32 + 4 * g2 + j;             // t=2 half
          else             F = 63;                          // zero pad slot
          if (F < KL) v = Wl[F * NL + n];                   // W^T: W[F][n]
          else if (F == KL) v = Bl[n];                      // bias row
        }
        lw[L * WSLOT + n * WSTRIDE + kp] = (_Float16)v;
      }
    }
  }

  __syncthreads();  // weights ready; only barrier in the kernel

  const char* xc = (const char*)x;
  const unsigned LIM = (unsigned)(XBYTES - 4);
  const unsigned blockbase = (unsigned)blockIdx.x * (ITERS * 256) + wave * 16;
  const f32x4 Z = {0.f, 0.f, 0.f, 0.f};   // shared MFMA C-init block

  // ---- x prefetch registers: 16 floats/lane = row (base+lr), k-slices
  //      [32g..32g+7] (q0,q1) and [128+32g..+7] (q2,q3; clamped, junk ok) ----
  f32x4 q0, q1, q2, q3;
  {
    unsigned rb = (blockbase + lr) * ROWB + 32u * g;
#pragma unroll
    for (int j = 0; j < 4; ++j) {
      q0[j] = *(const float*)(xc + (rb + 4u * j));
      q1[j] = *(const float*)(xc + (rb + 16u + 4u * j));
      unsigned a2 = rb + 128u + 4u * j;
      unsigned a3 = rb + 144u + 4u * j;
      q2[j] = *(const float*)(xc + (a2 < LIM ? a2 : LIM));
      q3[j] = *(const float*)(xc + (a3 < LIM ? a3 : LIM));
    }
  }

#pragma unroll 1
  for (int it = 0; it < ITERS; ++it) {
    const unsigned row0 = blockbase + (unsigned)it * 256u;

    // ---- layer-0 B-frag from registers; slot (c1,g=1,j=3) := 1.0 ----
    Frag2 B;
    {
      float e3 = (g == 1) ? 1.0f : q2[3];
      u32x4 d0 = {pk2(q0[0], q0[1]), pk2(q0[2], q0[3]),
                  pk2(q1[0], q1[1]), pk2(q1[2], q1[3])};
      u32x4 d1 = {pk2(q2[0], q2[1]), pk2(q2[2], e3),
                  pk2(q3[0], q3[1]), pk2(q3[2], q3[3])};
      B.c0 = __builtin_bit_cast(f16x8, d0);
      B.c1 = __builtin_bit_cast(f16x8, d1);
    }

    // ---- prefetch next iteration's x into registers ----
    if (it + 1 < ITERS) {
      unsigned rb = (row0 + 256u + lr) * ROWB + 32u * g;
#pragma unroll
      for (int j = 0; j < 4; ++j) {
        q0[j] = *(const float*)(xc + (rb + 4u * j));
        q1[j] = *(const float*)(xc + (rb + 16u + 4u * j));
        unsigned a2 = rb + 128u + 4u * j;
        unsigned a3 = rb + 144u + 4u * j;
        q2[j] = *(const float*)(xc + (a2 < LIM ? a2 : LIM));
        q3[j] = *(const float*)(xc + (a3 < LIM ? a3 : LIM));
      }
    }

    // ---- layers 0..8, hidden state entirely in registers ----
    B = layer_fwd<3, 2, true, 43, 2>(lw + 0 * WSLOT, B, Z, g, lr);
    B = layer_fwd<3, 2, true, 43, 2>(lw + 1 * WSLOT, B, Z, g, lr);
    B = layer_fwd<3, 2, true, 43, 2>(lw + 2 * WSLOT, B, Z, g, lr);
    B = layer_fwd<3, 2, true, 43, 2>(lw + 3 * WSLOT, B, Z, g, lr);
    B = layer_fwd<2, 2, false, 21, 1>(lw + 4 * WSLOT, B, Z, g, lr);
    B = layer_fwd<3, 1, true, 43, 2>(lw + 5 * WSLOT, B, Z, g, lr);
    B = layer_fwd<3, 2, true, 43, 2>(lw + 6 * WSLOT, B, Z, g, lr);
    B = layer_fwd<3, 2, true, 43, 2>(lw + 7 * WSLOT, B, Z, g, lr);
    B = layer_fwd<3, 2, true, 43, 2>(lw + 8 * WSLOT, B, Z, g, lr);

    // ---- layer 9: linear, store fp32 via base + immediate offsets ----
    {
      const _Float16* p = lw + 9 * WSLOT + lr * WSTRIDE + 8 * g;
      f32x4 a9[3];
      a9[0] = __builtin_amdgcn_mfma_f32_16x16x32_f16(*(const f16x8*)(p),
                                                     B.c0, Z, 0, 0, 0);
      a9[1] = __builtin_amdgcn_mfma_f32_16x16x32_f16(
          *(const f16x8*)(p + 16 * WSTRIDE), B.c0, Z, 0, 0, 0);
      a9[2] = __builtin_amdgcn_mfma_f32_16x16x32_f16(
          *(const f16x8*)(p + 32 * WSTRIDE), B.c0, Z, 0, 0, 0);
      a9[0] = __builtin_amdgcn_mfma_f32_16x16x32_f16(*(const f16x8*)(p + 32),
                                                     B.c1, a9[0], 0, 0, 0);
      a9[1] = __builtin_amdgcn_mfma_f32_16x16x32_f16(
          *(const f16x8*)(p + 16 * WSTRIDE + 32), B.c1, a9[1], 0, 0, 0);
      a9[2] = __builtin_amdgcn_mfma_f32_16x16x32_f16(
          *(const f16x8*)(p + 32 * WSTRIDE + 32), B.c1, a9[2], 0, 0, 0);

      char* ob = (char*)out + ((size_t)(row0 + lr) * ROWB + 16u * g);
#pragma unroll
      for (int t = 0; t < 3; ++t)
#pragma unroll
        for (int r = 0; r < 4; ++r) {
          // col = 16t + 4g + r < 43; t<2 always in range
          if (t < 2 || 4 * g + r < 11)
            *(float*)(ob + 64 * t + 4 * r) = a9[t][r];
        }
    }
  }
}

extern "C" void kernel_launch(void* const* d_in, const int* in_sizes, int n_in,
                              void* d_out, int out_size, void* d_ws,
                              size_t ws_size, hipStream_t stream) {
  const float* x = (const float*)d_in[0];
  const float* W[10];
  const float* B[10];
  for (int i = 0; i < 10; ++i) {
    W[i] = (const float*)d_in[1 + 2 * i];
    B[i] = (const float*)d_in[2 + 2 * i];
  }
  (void)hipFuncSetAttribute(reinterpret_cast<const void*>(ae_kernel),
                            hipFuncAttributeMaxDynamicSharedMemorySize,
                            SMEM_BYTES);
  ae_kernel<<<dim3(NBLK), dim3(TPB), SMEM_BYTES, stream>>>(
      x, W[0], B[0], W[1], B[1], W[2], B[2], W[3], B[3], W[4], B[4],
      W[5], B[5], W[6], B[6], W[7], B[7], W[8], B[8], W[9], B[9],
      (float*)d_out);
}

// Round 11
// 514.213 us; speedup vs baseline: 1.5113x; 1.5113x over previous
//
#include <hip/hip_runtime.h>

// SensorAutoEncoder: 10-layer MLP over 1M rows of 43 floats. fp16 MFMA
// (16x16x32) + fp32 accumulate. R11 = R10's register-resident chain with the
// occupancy unlock done right: NO LDS AT ALL in the main kernel. A tiny prep
// kernel writes the F-permuted fp16 W^T image (with bias rows) to d_ws; the
// main kernel reads A-fragments straight from global (L2-resident 63 KB,
// shared by all blocks), x lives in registers, hidden state in registers.
// -> 2 blocks/CU (thread-limited), ~8 waves/SIMD at natural VGPR allocation.
//   B slot (c,g,j): c==0 -> F = 16*(j>>2) + 4g + (j&3)
//                   c==1, j<4 -> F = 32 + 4g + j ; else zero pad
// bias via k==KL row; forced 1.0 multiplier at slot (c1,g=1,j=3); junk
// k-slots annihilated by zero A rows (rows 44..47 of slot L are slot L+1's
// finite weights; slot 9's overhang is zeroed by prep).

typedef __fp16 pk16x2 __attribute__((ext_vector_type(2)));   // cvt_pkrtz type
typedef _Float16 f16x8 __attribute__((ext_vector_type(8)));
typedef float f32x4 __attribute__((ext_vector_type(4)));
typedef unsigned u32x4 __attribute__((ext_vector_type(4)));

#define TPB 1024
#define NBLK 512
#define ITERS 8
#define NROWS 1048576
#define NCOL 43
#define ROWB 172u                        // bytes per x / out row (43 f32)
#define XBYTES ((size_t)NROWS * ROWB)    // 180,355,072
#define WSTRIDE 72                       // halfwords per W^T row (144 B)
#define SLOT_ROWS 44
#define WSLOT (SLOT_ROWS * WSTRIDE)      // 3168 halfwords per layer slot
#define W_HW (10 * WSLOT)                // 31680 halfwords
#define W_PAD_HW 320                     // layer-9 A-read overhang, zeroed
#define WS_BYTES ((W_HW + W_PAD_HW) * 2) // 64000 B needed in d_ws

__device__ __forceinline__ float fast_tanh(float x) {
  // tanh(x) = 1 - 2/(1 + e^{2x});  e^{2x} = 2^{x * 2*log2(e)}
  float t = __builtin_amdgcn_exp2f(x * 2.8853900817779268f);
  float r = __builtin_amdgcn_rcpf(t + 1.0f);
  return __builtin_fmaf(-2.0f, r, 1.0f);
}

__device__ __forceinline__ unsigned pk2(float a, float b) {
  pk16x2 h = __builtin_amdgcn_cvt_pkrtz(a, b);
  return __builtin_bit_cast(unsigned, h);
}

struct Frag2 { f16x8 c0, c1; };

// One layer: A-reads from the global weight image (L2-hit), MFMA (zero-C
// first chunk), epilogue (tanh + bias-column 1.0), pack into next B-frag.
template <int NT, int KC, bool DOTANH, int NLOUT, int KCN>
__device__ __forceinline__ Frag2 layer_fwd(const _Float16* __restrict__ Wl,
                                           Frag2 Bi, f32x4 Z, int g, int lr) {
  const _Float16* p = Wl + lr * WSTRIDE + 8 * g;
  f32x4 acc[3];
  acc[0] = __builtin_amdgcn_mfma_f32_16x16x32_f16(*(const f16x8*)(p),
                                                  Bi.c0, Z, 0, 0, 0);
  if constexpr (NT > 1)
    acc[1] = __builtin_amdgcn_mfma_f32_16x16x32_f16(
        *(const f16x8*)(p + 16 * WSTRIDE), Bi.c0, Z, 0, 0, 0);
  if constexpr (NT > 2)
    acc[2] = __builtin_amdgcn_mfma_f32_16x16x32_f16(
        *(const f16x8*)(p + 32 * WSTRIDE), Bi.c0, Z, 0, 0, 0);
  if constexpr (KC > 1) {
    acc[0] = __builtin_amdgcn_mfma_f32_16x16x32_f16(*(const f16x8*)(p + 32),
                                                    Bi.c1, acc[0], 0, 0, 0);
    if constexpr (NT > 1)
      acc[1] = __builtin_amdgcn_mfma_f32_16x16x32_f16(
          *(const f16x8*)(p + 16 * WSTRIDE + 32), Bi.c1, acc[1], 0, 0, 0);
    if constexpr (NT > 2)
      acc[2] = __builtin_amdgcn_mfma_f32_16x16x32_f16(
          *(const f16x8*)(p + 32 * WSTRIDE + 32), Bi.c1, acc[2], 0, 0, 0);
  }

  unsigned pk[3][2];
#pragma unroll
  for (int t = 0; t < NT; ++t) {
    float v[4];
#pragma unroll
    for (int r = 0; r < 4; ++r) {
      float u = acc[t][r];
      if (DOTANH) u = fast_tanh(u);
      if (t == (NLOUT >> 4)) {                 // bias-mult column -> 1.0
        int col = 16 * t + 4 * g + r;
        u = (col == NLOUT) ? 1.0f : u;
      }
      v[r] = u;
    }
    pk[t][0] = pk2(v[0], v[1]);
    pk[t][1] = pk2(v[2], v[3]);
  }
  Frag2 O;
  u32x4 d0 = {pk[0][0], pk[0][1], pk[1][0], pk[1][1]};
  O.c0 = __builtin_bit_cast(f16x8, d0);
  if (KCN == 2) {
    u32x4 d1 = {pk[NT - 1][0], pk[NT - 1][1], 0u, 0u};
    O.c1 = __builtin_bit_cast(f16x8, d1);
  } else {
    O.c1 = O.c0;   // unused by a KC=1 consumer
  }
  return O;
}

// ---- prep: build the F-permuted fp16 W^T image (+bias rows) in d_ws ----
extern "C" __global__ void __launch_bounds__(TPB)
ae_prep(const float* __restrict__ W0, const float* __restrict__ B0,
        const float* __restrict__ W1, const float* __restrict__ B1,
        const float* __restrict__ W2, const float* __restrict__ B2,
        const float* __restrict__ W3, const float* __restrict__ B3,
        const float* __restrict__ W4, const float* __restrict__ B4,
        const float* __restrict__ W5, const float* __restrict__ B5,
        const float* __restrict__ W6, const float* __restrict__ B6,
        const float* __restrict__ W7, const float* __restrict__ B7,
        const float* __restrict__ W8, const float* __restrict__ B8,
        const float* __restrict__ W9, const float* __restrict__ B9,
        _Float16* __restrict__ wg) {
  const int tid = threadIdx.x;
  const float* Wp[10] = {W0, W1, W2, W3, W4, W5, W6, W7, W8, W9};
  const float* Bp[10] = {B0, B1, B2, B3, B4, B5, B6, B7, B8, B9};
  const int KLs[10] = {43, 43, 43, 43, 43, 21, 43, 43, 43, 43};
  const int NLs[10] = {43, 43, 43, 43, 21, 43, 43, 43, 43, 43};
  for (int idx = tid; idx < 10 * SLOT_ROWS * 64; idx += TPB) {
    int L = idx / (SLOT_ROWS * 64);
    int rem = idx - L * (SLOT_ROWS * 64);
    int n = rem >> 6, kp = rem & 63;
    const int KL = KLs[L], NL = NLs[L];
    float v = 0.0f;
    if (n < NL) {
      int c = kp >> 5, g2 = (kp >> 3) & 3, j = kp & 7;
      int F;
      if (L == 0) F = kp;                               // natural
      else if (c == 0) F = 16 * (j >> 2) + 4 * g2 + (j & 3);
      else if (j < 4)  F = 32 + 4 * g2 + j;             // t=2 half
      else             F = 63;                          // zero pad slot
      if (F < KL) v = Wp[L][F * NL + n];                // W^T: W[F][n]
      else if (F == KL) v = Bp[L][n];                   // bias row
    }
    wg[L * WSLOT + n * WSTRIDE + kp] = (_Float16)v;
  }
  if (tid < W_PAD_HW) wg[W_HW + tid] = (_Float16)0.0f;  // layer-9 overhang
}

extern "C" __global__ void __launch_bounds__(TPB)
ae_kernel(const float* __restrict__ x, const _Float16* __restrict__ wg,
          float* __restrict__ out) {
  const int tid = threadIdx.x;
  const int wave = tid >> 6;
  const int lane = tid & 63;
  const int g = lane >> 4;
  const int lr = lane & 15;

  const char* xc = (const char*)x;
  const unsigned LIM = (unsigned)(XBYTES - 4);
  const unsigned blockbase = (unsigned)blockIdx.x * (ITERS * 256) + wave * 16;
  const f32x4 Z = {0.f, 0.f, 0.f, 0.f};   // shared MFMA C-init block

  // ---- x prefetch registers: 16 floats/lane = row (base+lr), k-slices
  //      [32g..32g+7] (q0,q1) and [128+32g..+7] (q2,q3; clamped, junk ok) ----
  f32x4 q0, q1, q2, q3;
  {
    unsigned rb = (blockbase + lr) * ROWB + 32u * g;
#pragma unroll
    for (int j = 0; j < 4; ++j) {
      q0[j] = *(const float*)(xc + (rb + 4u * j));
      q1[j] = *(const float*)(xc + (rb + 16u + 4u * j));
      unsigned a2 = rb + 128u + 4u * j;
      unsigned a3 = rb + 144u + 4u * j;
      q2[j] = *(const float*)(xc + (a2 < LIM ? a2 : LIM));
      q3[j] = *(const float*)(xc + (a3 < LIM ? a3 : LIM));
    }
  }

#pragma unroll 1
  for (int it = 0; it < ITERS; ++it) {
    const unsigned row0 = blockbase + (unsigned)it * 256u;

    // ---- layer-0 B-frag from registers; slot (c1,g=1,j=3) := 1.0 ----
    Frag2 B;
    {
      float e3 = (g == 1) ? 1.0f : q2[3];
      u32x4 d0 = {pk2(q0[0], q0[1]), pk2(q0[2], q0[3]),
                  pk2(q1[0], q1[1]), pk2(q1[2], q1[3])};
      u32x4 d1 = {pk2(q2[0], q2[1]), pk2(q2[2], e3),
                  pk2(q3[0], q3[1]), pk2(q3[2], q3[3])};
      B.c0 = __builtin_bit_cast(f16x8, d0);
      B.c1 = __builtin_bit_cast(f16x8, d1);
    }

    // ---- prefetch next iteration's x into registers ----
    if (it + 1 < ITERS) {
      unsigned rb = (row0 + 256u + lr) * ROWB + 32u * g;
#pragma unroll
      for (int j = 0; j < 4; ++j) {
        q0[j] = *(const float*)(xc + (rb + 4u * j));
        q1[j] = *(const float*)(xc + (rb + 16u + 4u * j));
        unsigned a2 = rb + 128u + 4u * j;
        unsigned a3 = rb + 144u + 4u * j;
        q2[j] = *(const float*)(xc + (a2 < LIM ? a2 : LIM));
        q3[j] = *(const float*)(xc + (a3 < LIM ? a3 : LIM));
      }
    }

    // ---- layers 0..8, hidden state entirely in registers ----
    B = layer_fwd<3, 2, true, 43, 2>(wg + 0 * WSLOT, B, Z, g, lr);
    B = layer_fwd<3, 2, true, 43, 2>(wg + 1 * WSLOT, B, Z, g, lr);
    B = layer_fwd<3, 2, true, 43, 2>(wg + 2 * WSLOT, B, Z, g, lr);
    B = layer_fwd<3, 2, true, 43, 2>(wg + 3 * WSLOT, B, Z, g, lr);
    B = layer_fwd<2, 2, false, 21, 1>(wg + 4 * WSLOT, B, Z, g, lr);
    B = layer_fwd<3, 1, true, 43, 2>(wg + 5 * WSLOT, B, Z, g, lr);
    B = layer_fwd<3, 2, true, 43, 2>(wg + 6 * WSLOT, B, Z, g, lr);
    B = layer_fwd<3, 2, true, 43, 2>(wg + 7 * WSLOT, B, Z, g, lr);
    B = layer_fwd<3, 2, true, 43, 2>(wg + 8 * WSLOT, B, Z, g, lr);

    // ---- layer 9: linear, store fp32 via base + immediate offsets ----
    {
      const _Float16* p = wg + 9 * WSLOT + lr * WSTRIDE + 8 * g;
      f32x4 a9[3];
      a9[0] = __builtin_amdgcn_mfma_f32_16x16x32_f16(*(const f16x8*)(p),
                                                     B.c0, Z, 0, 0, 0);
      a9[1] = __builtin_amdgcn_mfma_f32_16x16x32_f16(
          *(const f16x8*)(p + 16 * WSTRIDE), B.c0, Z, 0, 0, 0);
      a9[2] = __builtin_amdgcn_mfma_f32_16x16x32_f16(
          *(const f16x8*)(p + 32 * WSTRIDE), B.c0, Z, 0, 0, 0);
      a9[0] = __builtin_amdgcn_mfma_f32_16x16x32_f16(*(const f16x8*)(p + 32),
                                                     B.c1, a9[0], 0, 0, 0);
      a9[1] = __builtin_amdgcn_mfma_f32_16x16x32_f16(
          *(const f16x8*)(p + 16 * WSTRIDE + 32), B.c1, a9[1], 0, 0, 0);
      a9[2] = __builtin_amdgcn_mfma_f32_16x16x32_f16(
          *(const f16x8*)(p + 32 * WSTRIDE + 32), B.c1, a9[2], 0, 0, 0);

      char* ob = (char*)out + ((size_t)(row0 + lr) * ROWB + 16u * g);
#pragma unroll
      for (int t = 0; t < 3; ++t)
#pragma unroll
        for (int r = 0; r < 4; ++r) {
          // col = 16t + 4g + r < 43; t<2 always in range
          if (t < 2 || 4 * g + r < 11)
            *(float*)(ob + 64 * t + 4 * r) = a9[t][r];
        }
    }
  }
}

extern "C" void kernel_launch(void* const* d_in, const int* in_sizes, int n_in,
                              void* d_out, int out_size, void* d_ws,
                              size_t ws_size, hipStream_t stream) {
  const float* x = (const float*)d_in[0];
  const float* W[10];
  const float* B[10];
  for (int i = 0; i < 10; ++i) {
    W[i] = (const float*)d_in[1 + 2 * i];
    B[i] = (const float*)d_in[2 + 2 * i];
  }
  _Float16* wg = (_Float16*)d_ws;
  ae_prep<<<dim3(1), dim3(TPB), 0, stream>>>(
      W[0], B[0], W[1], B[1], W[2], B[2], W[3], B[3], W[4], B[4],
      W[5], B[5], W[6], B[6], W[7], B[7], W[8], B[8], W[9], B[9], wg);
  ae_kernel<<<dim3(NBLK), dim3(TPB), 0, stream>>>(x, wg, (float*)d_out);
}

// Round 12
// 457.984 us; speedup vs baseline: 1.6969x; 1.1228x over previous
//
#include <hip/hip_runtime.h>

// SensorAutoEncoder: 10-layer MLP over 1M rows of 43 floats. fp16 MFMA
// (16x16x32) + fp32 accumulate. R12 = R10's M=16/wave register-resident chain
// + LDS restored to WEIGHTS ONLY (64,000 B -> 2 blocks/CU co-resident) +
// x loaded JIT (no prefetch registers; 8-wave TLP hides the load latency) +
// natural register allocation (no min-waves launch bound -> no forced spill).
//   B slot (c,g,j): c==0 -> F = 16*(j>>2) + 4g + (j&3)
//                   c==1, j<4 -> F = 32 + 4g + j ; else zero pad
// k-permutation F folded into weight staging; bias via k==KL row; forced 1.0
// multiplier at slot (c1,g=1,j=3); junk k-slots annihilated by zero A rows;
// layer-9 A-read overhang (rows 44..47) covered by zeroed pad.

typedef __fp16 pk16x2 __attribute__((ext_vector_type(2)));   // cvt_pkrtz type
typedef _Float16 f16x8 __attribute__((ext_vector_type(8)));
typedef float f32x4 __attribute__((ext_vector_type(4)));
typedef unsigned u32x4 __attribute__((ext_vector_type(4)));

#define TPB 1024
#define NBLK 512
#define ITERS 8
#define NROWS 1048576
#define NCOL 43
#define ROWB 172u                        // bytes per x / out row (43 f32)
#define XBYTES ((size_t)NROWS * ROWB)    // 180,355,072
#define WSTRIDE 72                       // halfwords per W^T row (144 B)
#define SLOT_ROWS 44
#define WSLOT (SLOT_ROWS * WSTRIDE)      // 3168 halfwords per layer slot
#define W_HW (10 * WSLOT)                // 31680 halfwords
#define W_PAD_HW 320                     // layer-9 overhang rows, zeroed
#define SMEM_BYTES ((W_HW + W_PAD_HW) * 2)  // 64000 B -> 2 blocks/CU

__device__ __forceinline__ float fast_tanh(float x) {
  // tanh(x) = 1 - 2/(1 + e^{2x});  e^{2x} = 2^{x * 2*log2(e)}
  float t = __builtin_amdgcn_exp2f(x * 2.8853900817779268f);
  float r = __builtin_amdgcn_rcpf(t + 1.0f);
  return __builtin_fmaf(-2.0f, r, 1.0f);
}

__device__ __forceinline__ unsigned pk2(float a, float b) {
  pk16x2 h = __builtin_amdgcn_cvt_pkrtz(a, b);
  return __builtin_bit_cast(unsigned, h);
}

struct Frag2 { f16x8 c0, c1; };

// One layer: JIT A-reads from LDS weights, MFMA (zero-C first chunk),
// epilogue (tanh + bias-column 1.0 forcing), pack into next B-frag.
template <int NT, int KC, bool DOTANH, int NLOUT, int KCN>
__device__ __forceinline__ Frag2 layer_fwd(const _Float16* __restrict__ Wl,
                                           Frag2 Bi, f32x4 Z, int g, int lr) {
  const _Float16* p = Wl + lr * WSTRIDE + 8 * g;
  f32x4 acc[3];
  acc[0] = __builtin_amdgcn_mfma_f32_16x16x32_f16(*(const f16x8*)(p),
                                                  Bi.c0, Z, 0, 0, 0);
  if constexpr (NT > 1)
    acc[1] = __builtin_amdgcn_mfma_f32_16x16x32_f16(
        *(const f16x8*)(p + 16 * WSTRIDE), Bi.c0, Z, 0, 0, 0);
  if constexpr (NT > 2)
    acc[2] = __builtin_amdgcn_mfma_f32_16x16x32_f16(
        *(const f16x8*)(p + 32 * WSTRIDE), Bi.c0, Z, 0, 0, 0);
  if constexpr (KC > 1) {
    acc[0] = __builtin_amdgcn_mfma_f32_16x16x32_f16(*(const f16x8*)(p + 32),
                                                    Bi.c1, acc[0], 0, 0, 0);
    if constexpr (NT > 1)
      acc[1] = __builtin_amdgcn_mfma_f32_16x16x32_f16(
          *(const f16x8*)(p + 16 * WSTRIDE + 32), Bi.c1, acc[1], 0, 0, 0);
    if constexpr (NT > 2)
      acc[2] = __builtin_amdgcn_mfma_f32_16x16x32_f16(
          *(const f16x8*)(p + 32 * WSTRIDE + 32), Bi.c1, acc[2], 0, 0, 0);
  }

  unsigned pk[3][2];
#pragma unroll
  for (int t = 0; t < NT; ++t) {
    float v[4];
#pragma unroll
    for (int r = 0; r < 4; ++r) {
      float u = acc[t][r];
      if (DOTANH) u = fast_tanh(u);
      if (t == (NLOUT >> 4)) {                 // bias-mult column -> 1.0
        int col = 16 * t + 4 * g + r;
        u = (col == NLOUT) ? 1.0f : u;
      }
      v[r] = u;
    }
    pk[t][0] = pk2(v[0], v[1]);
    pk[t][1] = pk2(v[2], v[3]);
  }
  Frag2 O;
  u32x4 d0 = {pk[0][0], pk[0][1], pk[1][0], pk[1][1]};
  O.c0 = __builtin_bit_cast(f16x8, d0);
  if (KCN == 2) {
    u32x4 d1 = {pk[NT - 1][0], pk[NT - 1][1], 0u, 0u};
    O.c1 = __builtin_bit_cast(f16x8, d1);
  } else {
    O.c1 = O.c0;   // unused by a KC=1 consumer
  }
  return O;
}

extern "C" __global__ void __launch_bounds__(TPB)
ae_kernel(const float* __restrict__ x,
          const float* __restrict__ W0, const float* __restrict__ B0,
          const float* __restrict__ W1, const float* __restrict__ B1,
          const float* __restrict__ W2, const float* __restrict__ B2,
          const float* __restrict__ W3, const float* __restrict__ B3,
          const float* __restrict__ W4, const float* __restrict__ B4,
          const float* __restrict__ W5, const float* __restrict__ B5,
          const float* __restrict__ W6, const float* __restrict__ B6,
          const float* __restrict__ W7, const float* __restrict__ B7,
          const float* __restrict__ W8, const float* __restrict__ B8,
          const float* __restrict__ W9, const float* __restrict__ B9,
          float* __restrict__ out) {
  extern __shared__ char smem[];
  _Float16* lw = (_Float16*)smem;

  const int tid = threadIdx.x;
  const int wave = tid >> 6;
  const int lane = tid & 63;
  const int g = lane >> 4;
  const int lr = lane & 15;

  // ---- stage weights as fp16 W^T (k-permutation F for layers 1..9), bias
  //      at the slot mapping to k==KL; 44 rows per slot; zero the pad ----
  {
    const float* Wp[10] = {W0, W1, W2, W3, W4, W5, W6, W7, W8, W9};
    const float* Bp[10] = {B0, B1, B2, B3, B4, B5, B6, B7, B8, B9};
    const int KLs[10] = {43, 43, 43, 43, 43, 21, 43, 43, 43, 43};
    const int NLs[10] = {43, 43, 43, 43, 21, 43, 43, 43, 43, 43};
#pragma unroll
    for (int L = 0; L < 10; ++L) {
      const float* Wl = Wp[L];
      const float* Bl = Bp[L];
      const int KL = KLs[L], NL = NLs[L];
      for (int idx = tid; idx < SLOT_ROWS * 64; idx += TPB) {
        int n = idx >> 6, kp = idx & 63;
        float v = 0.0f;
        if (n < NL) {
          int c = kp >> 5, g2 = (kp >> 3) & 3, j = kp & 7;
          int F;
          if (L == 0) F = kp;                               // natural
          else if (c == 0) F = 16 * (j >> 2) + 4 * g2 + (j & 3);
          else if (j < 4)  F = 32 + 4 * g2 + j;             // t=2 half
          else             F = 63;                          // zero pad slot
          if (F < KL) v = Wl[F * NL + n];                   // W^T: W[F][n]
          else if (F == KL) v = Bl[n];                      // bias row
        }
        lw[L * WSLOT + n * WSTRIDE + kp] = (_Float16)v;
      }
    }
    if (tid < W_PAD_HW) lw[W_HW + tid] = (_Float16)0.0f;
  }

  __syncthreads();  // weights ready; only barrier in the kernel

  const char* xc = (const char*)x;
  const unsigned LIM = (unsigned)(XBYTES - 4);
  const unsigned blockbase = (unsigned)blockIdx.x * (ITERS * 256) + wave * 16;
  const f32x4 Z = {0.f, 0.f, 0.f, 0.f};   // shared MFMA C-init block

#pragma unroll 1
  for (int it = 0; it < ITERS; ++it) {
    const unsigned row0 = blockbase + (unsigned)it * 256u;

    // ---- load this iteration's x JIT (16 clamped scalar dwords); TLP at
    //      8 waves/SIMD hides the latency; registers die after frag build ----
    Frag2 B;
    {
      unsigned rb = (row0 + lr) * ROWB + 32u * g;
      f32x4 q0, q1, q2, q3;
#pragma unroll
      for (int j = 0; j < 4; ++j) {
        q0[j] = *(const float*)(xc + (rb + 4u * j));
        q1[j] = *(const float*)(xc + (rb + 16u + 4u * j));
        unsigned a2 = rb + 128u + 4u * j;
        unsigned a3 = rb + 144u + 4u * j;
        q2[j] = *(const float*)(xc + (a2 < LIM ? a2 : LIM));
        q3[j] = *(const float*)(xc + (a3 < LIM ? a3 : LIM));
      }
      float e3 = (g == 1) ? 1.0f : q2[3];   // k==43 bias multiplier
      u32x4 d0 = {pk2(q0[0], q0[1]), pk2(q0[2], q0[3]),
                  pk2(q1[0], q1[1]), pk2(q1[2], q1[3])};
      u32x4 d1 = {pk2(q2[0], q2[1]), pk2(q2[2], e3),
                  pk2(q3[0], q3[1]), pk2(q3[2], q3[3])};
      B.c0 = __builtin_bit_cast(f16x8, d0);
      B.c1 = __builtin_bit_cast(f16x8, d1);
    }

    // ---- layers 0..8, hidden state entirely in registers ----
    B = layer_fwd<3, 2, true, 43, 2>(lw + 0 * WSLOT, B, Z, g, lr);
    B = layer_fwd<3, 2, true, 43, 2>(lw + 1 * WSLOT, B, Z, g, lr);
    B = layer_fwd<3, 2, true, 43, 2>(lw + 2 * WSLOT, B, Z, g, lr);
    B = layer_fwd<3, 2, true, 43, 2>(lw + 3 * WSLOT, B, Z, g, lr);
    B = layer_fwd<2, 2, false, 21, 1>(lw + 4 * WSLOT, B, Z, g, lr);
    B = layer_fwd<3, 1, true, 43, 2>(lw + 5 * WSLOT, B, Z, g, lr);
    B = layer_fwd<3, 2, true, 43, 2>(lw + 6 * WSLOT, B, Z, g, lr);
    B = layer_fwd<3, 2, true, 43, 2>(lw + 7 * WSLOT, B, Z, g, lr);
    B = layer_fwd<3, 2, true, 43, 2>(lw + 8 * WSLOT, B, Z, g, lr);

    // ---- layer 9: linear, store fp32 via base + immediate offsets ----
    {
      const _Float16* p = lw + 9 * WSLOT + lr * WSTRIDE + 8 * g;
      f32x4 a9[3];
      a9[0] = __builtin_amdgcn_mfma_f32_16x16x32_f16(*(const f16x8*)(p),
                                                     B.c0, Z, 0, 0, 0);
      a9[1] = __builtin_amdgcn_mfma_f32_16x16x32_f16(
          *(const f16x8*)(p + 16 * WSTRIDE), B.c0, Z, 0, 0, 0);
      a9[2] = __builtin_amdgcn_mfma_f32_16x16x32_f16(
          *(const f16x8*)(p + 32 * WSTRIDE), B.c0, Z, 0, 0, 0);
      a9[0] = __builtin_amdgcn_mfma_f32_16x16x32_f16(*(const f16x8*)(p + 32),
                                                     B.c1, a9[0], 0, 0, 0);
      a9[1] = __builtin_amdgcn_mfma_f32_16x16x32_f16(
          *(const f16x8*)(p + 16 * WSTRIDE + 32), B.c1, a9[1], 0, 0, 0);
      a9[2] = __builtin_amdgcn_mfma_f32_16x16x32_f16(
          *(const f16x8*)(p + 32 * WSTRIDE + 32), B.c1, a9[2], 0, 0, 0);

      char* ob = (char*)out + ((size_t)(row0 + lr) * ROWB + 16u * g);
#pragma unroll
      for (int t = 0; t < 3; ++t)
#pragma unroll
        for (int r = 0; r < 4; ++r) {
          // col = 16t + 4g + r < 43; t<2 always in range
          if (t < 2 || 4 * g + r < 11)
            *(float*)(ob + 64 * t + 4 * r) = a9[t][r];
        }
    }
  }
}

extern "C" void kernel_launch(void* const* d_in, const int* in_sizes, int n_in,
                              void* d_out, int out_size, void* d_ws,
                              size_t ws_size, hipStream_t stream) {
  const float* x = (const float*)d_in[0];
  const float* W[10];
  const float* B[10];
  for (int i = 0; i < 10; ++i) {
    W[i] = (const float*)d_in[1 + 2 * i];
    B[i] = (const float*)d_in[2 + 2 * i];
  }
  (void)hipFuncSetAttribute(reinterpret_cast<const void*>(ae_kernel),
                            hipFuncAttributeMaxDynamicSharedMemorySize,
                            SMEM_BYTES);
  ae_kernel<<<dim3(NBLK), dim3(TPB), SMEM_BYTES, stream>>>(
      x, W[0], B[0], W[1], B[1], W[2], B[2], W[3], B[3], W[4], B[4],
      W[5], B[5], W[6], B[6], W[7], B[7], W[8], B[8], W[9], B[9],
      (float*)d_out);
}

// Round 13
// 412.664 us; speedup vs baseline: 1.8832x; 1.1098x over previous
//
#include <hip/hip_runtime.h>

// SensorAutoEncoder: 10-layer MLP over 1M rows of 43 floats. fp16 MFMA
// (16x16x32) + fp32 accumulate. R13 = R12 (LDS = weights only, 64,000 B ->
// 2 blocks/CU; M=16/wave; register-resident F-permuted layer chain) with the
// x-load phase slimmed to fit the compiler's 64-VGPR target without spill:
// blocks 0..NBLK-2 load x via ONE per-lane base pointer + immediate offsets
// (overrun <= 80 B stays inside the buffer for rows < N-1; junk k-slots are
// annihilated by zero A rows). Only the LAST block (owning the final row)
// runs the per-element clamped path. Block-uniform branch.
//   B slot (c,g,j): c==0 -> F = 16*(j>>2) + 4g + (j&3)
//                   c==1, j<4 -> F = 32 + 4g + j ; else zero pad
// bias via k==KL row; forced 1.0 multiplier at slot (c1,g=1,j=3).

typedef __fp16 pk16x2 __attribute__((ext_vector_type(2)));   // cvt_pkrtz type
typedef _Float16 f16x8 __attribute__((ext_vector_type(8)));
typedef float f32x4 __attribute__((ext_vector_type(4)));
typedef unsigned u32x4 __attribute__((ext_vector_type(4)));

#define TPB 1024
#define NBLK 512
#define ITERS 8
#define NROWS 1048576
#define NCOL 43
#define ROWB 172u                        // bytes per x / out row (43 f32)
#define XBYTES ((size_t)NROWS * ROWB)    // 180,355,072
#define WSTRIDE 72                       // halfwords per W^T row (144 B)
#define SLOT_ROWS 44
#define WSLOT (SLOT_ROWS * WSTRIDE)      // 3168 halfwords per layer slot
#define W_HW (10 * WSLOT)                // 31680 halfwords
#define W_PAD_HW 320                     // layer-9 overhang rows, zeroed
#define SMEM_BYTES ((W_HW + W_PAD_HW) * 2)  // 64000 B -> 2 blocks/CU

__device__ __forceinline__ float fast_tanh(float x) {
  // tanh(x) = 1 - 2/(1 + e^{2x});  e^{2x} = 2^{x * 2*log2(e)}
  float t = __builtin_amdgcn_exp2f(x * 2.8853900817779268f);
  float r = __builtin_amdgcn_rcpf(t + 1.0f);
  return __builtin_fmaf(-2.0f, r, 1.0f);
}

__device__ __forceinline__ unsigned pk2(float a, float b) {
  pk16x2 h = __builtin_amdgcn_cvt_pkrtz(a, b);
  return __builtin_bit_cast(unsigned, h);
}

struct Frag2 { f16x8 c0, c1; };

// Build the layer-0 B-frag for row (rb = row*172 + 32g bytes into x).
// CLAMP=false: single base pointer + immediate offsets (2 addr VGPRs).
// CLAMP=true (last block only): per-element clamp to the buffer end.
template <bool CLAMP>
__device__ __forceinline__ Frag2 build_b0(const char* __restrict__ xc,
                                          unsigned rb, int g) {
  f32x4 q0, q1, q2, q3;
  if constexpr (CLAMP) {
    const unsigned LIM = (unsigned)(XBYTES - 4);
#pragma unroll
    for (int j = 0; j < 4; ++j) {
      q0[j] = *(const float*)(xc + (rb + 4u * j));
      q1[j] = *(const float*)(xc + (rb + 16u + 4u * j));
      unsigned a2 = rb + 128u + 4u * j;
      unsigned a3 = rb + 144u + 4u * j;
      q2[j] = *(const float*)(xc + (a2 < LIM ? a2 : LIM));
      q3[j] = *(const float*)(xc + (a3 < LIM ? a3 : LIM));
    }
  } else {
    const char* p = xc + rb;
#pragma unroll
    for (int j = 0; j < 4; ++j) {
      q0[j] = *(const float*)(p + 4 * j);
      q1[j] = *(const float*)(p + 16 + 4 * j);
      q2[j] = *(const float*)(p + 128 + 4 * j);   // rows < N-1: overrun <=80B
      q3[j] = *(const float*)(p + 144 + 4 * j);   // stays in-buffer; junk ok
    }
  }
  float e3 = (g == 1) ? 1.0f : q2[3];   // k==43 bias multiplier := 1.0
  u32x4 d0 = {pk2(q0[0], q0[1]), pk2(q0[2], q0[3]),
              pk2(q1[0], q1[1]), pk2(q1[2], q1[3])};
  u32x4 d1 = {pk2(q2[0], q2[1]), pk2(q2[2], e3),
              pk2(q3[0], q3[1]), pk2(q3[2], q3[3])};
  Frag2 B;
  B.c0 = __builtin_bit_cast(f16x8, d0);
  B.c1 = __builtin_bit_cast(f16x8, d1);
  return B;
}

// One layer: JIT A-reads from LDS weights, MFMA (zero-C first chunk),
// epilogue (tanh + bias-column 1.0 forcing), pack into next B-frag.
template <int NT, int KC, bool DOTANH, int NLOUT, int KCN>
__device__ __forceinline__ Frag2 layer_fwd(const _Float16* __restrict__ Wl,
                                           Frag2 Bi, f32x4 Z, int g, int lr) {
  const _Float16* p = Wl + lr * WSTRIDE + 8 * g;
  f32x4 acc[3];
  acc[0] = __builtin_amdgcn_mfma_f32_16x16x32_f16(*(const f16x8*)(p),
                                                  Bi.c0, Z, 0, 0, 0);
  if constexpr (NT > 1)
    acc[1] = __builtin_amdgcn_mfma_f32_16x16x32_f16(
        *(const f16x8*)(p + 16 * WSTRIDE), Bi.c0, Z, 0, 0, 0);
  if constexpr (NT > 2)
    acc[2] = __builtin_amdgcn_mfma_f32_16x16x32_f16(
        *(const f16x8*)(p + 32 * WSTRIDE), Bi.c0, Z, 0, 0, 0);
  if constexpr (KC > 1) {
    acc[0] = __builtin_amdgcn_mfma_f32_16x16x32_f16(*(const f16x8*)(p + 32),
                                                    Bi.c1, acc[0], 0, 0, 0);
    if constexpr (NT > 1)
      acc[1] = __builtin_amdgcn_mfma_f32_16x16x32_f16(
          *(const f16x8*)(p + 16 * WSTRIDE + 32), Bi.c1, acc[1], 0, 0, 0);
    if constexpr (NT > 2)
      acc[2] = __builtin_amdgcn_mfma_f32_16x16x32_f16(
          *(const f16x8*)(p + 32 * WSTRIDE + 32), Bi.c1, acc[2], 0, 0, 0);
  }

  unsigned pk[3][2];
#pragma unroll
  for (int t = 0; t < NT; ++t) {
    float v[4];
#pragma unroll
    for (int r = 0; r < 4; ++r) {
      float u = acc[t][r];
      if (DOTANH) u = fast_tanh(u);
      if (t == (NLOUT >> 4)) {                 // bias-mult column -> 1.0
        int col = 16 * t + 4 * g + r;
        u = (col == NLOUT) ? 1.0f : u;
      }
      v[r] = u;
    }
    pk[t][0] = pk2(v[0], v[1]);
    pk[t][1] = pk2(v[2], v[3]);
  }
  Frag2 O;
  u32x4 d0 = {pk[0][0], pk[0][1], pk[1][0], pk[1][1]};
  O.c0 = __builtin_bit_cast(f16x8, d0);
  if (KCN == 2) {
    u32x4 d1 = {pk[NT - 1][0], pk[NT - 1][1], 0u, 0u};
    O.c1 = __builtin_bit_cast(f16x8, d1);
  } else {
    O.c1 = O.c0;   // unused by a KC=1 consumer
  }
  return O;
}

extern "C" __global__ void __launch_bounds__(TPB)
ae_kernel(const float* __restrict__ x,
          const float* __restrict__ W0, const float* __restrict__ B0,
          const float* __restrict__ W1, const float* __restrict__ B1,
          const float* __restrict__ W2, const float* __restrict__ B2,
          const float* __restrict__ W3, const float* __restrict__ B3,
          const float* __restrict__ W4, const float* __restrict__ B4,
          const float* __restrict__ W5, const float* __restrict__ B5,
          const float* __restrict__ W6, const float* __restrict__ B6,
          const float* __restrict__ W7, const float* __restrict__ B7,
          const float* __restrict__ W8, const float* __restrict__ B8,
          const float* __restrict__ W9, const float* __restrict__ B9,
          float* __restrict__ out) {
  extern __shared__ char smem[];
  _Float16* lw = (_Float16*)smem;

  const int tid = threadIdx.x;
  const int wave = tid >> 6;
  const int lane = tid & 63;
  const int g = lane >> 4;
  const int lr = lane & 15;

  // ---- stage weights as fp16 W^T (k-permutation F for layers 1..9), bias
  //      at the slot mapping to k==KL; 44 rows per slot; zero the pad ----
  {
    const float* Wp[10] = {W0, W1, W2, W3, W4, W5, W6, W7, W8, W9};
    const float* Bp[10] = {B0, B1, B2, B3, B4, B5, B6, B7, B8, B9};
    const int KLs[10] = {43, 43, 43, 43, 43, 21, 43, 43, 43, 43};
    const int NLs[10] = {43, 43, 43, 43, 21, 43, 43, 43, 43, 43};
#pragma unroll
    for (int L = 0; L < 10; ++L) {
      const float* Wl = Wp[L];
      const float* Bl = Bp[L];
      const int KL = KLs[L], NL = NLs[L];
      for (int idx = tid; idx < SLOT_ROWS * 64; idx += TPB) {
        int n = idx >> 6, kp = idx & 63;
        float v = 0.0f;
        if (n < NL) {
          int c = kp >> 5, g2 = (kp >> 3) & 3, j = kp & 7;
          int F;
          if (L == 0) F = kp;                               // natural
          else if (c == 0) F = 16 * (j >> 2) + 4 * g2 + (j & 3);
          else if (j < 4)  F = 32 + 4 * g2 + j;             // t=2 half
          else             F = 63;                          // zero pad slot
          if (F < KL) v = Wl[F * NL + n];                   // W^T: W[F][n]
          else if (F == KL) v = Bl[n];                      // bias row
        }
        lw[L * WSLOT + n * WSTRIDE + kp] = (_Float16)v;
      }
    }
    if (tid < W_PAD_HW) lw[W_HW + tid] = (_Float16)0.0f;
  }

  __syncthreads();  // weights ready; only barrier in the kernel

  const char* xc = (const char*)x;
  const unsigned blockbase = (unsigned)blockIdx.x * (ITERS * 256) + wave * 16;
  const bool lastblk = (blockIdx.x == NBLK - 1);
  const f32x4 Z = {0.f, 0.f, 0.f, 0.f};   // shared MFMA C-init block

#pragma unroll 1
  for (int it = 0; it < ITERS; ++it) {
    const unsigned row0 = blockbase + (unsigned)it * 256u;
    const unsigned rb = (row0 + lr) * ROWB + 32u * g;

    // ---- layer-0 B-frag (fast path except the last block) ----
    Frag2 B = lastblk ? build_b0<true>(xc, rb, g)
                      : build_b0<false>(xc, rb, g);

    // ---- layers 0..8, hidden state entirely in registers ----
    B = layer_fwd<3, 2, true, 43, 2>(lw + 0 * WSLOT, B, Z, g, lr);
    B = layer_fwd<3, 2, true, 43, 2>(lw + 1 * WSLOT, B, Z, g, lr);
    B = layer_fwd<3, 2, true, 43, 2>(lw + 2 * WSLOT, B, Z, g, lr);
    B = layer_fwd<3, 2, true, 43, 2>(lw + 3 * WSLOT, B, Z, g, lr);
    B = layer_fwd<2, 2, false, 21, 1>(lw + 4 * WSLOT, B, Z, g, lr);
    B = layer_fwd<3, 1, true, 43, 2>(lw + 5 * WSLOT, B, Z, g, lr);
    B = layer_fwd<3, 2, true, 43, 2>(lw + 6 * WSLOT, B, Z, g, lr);
    B = layer_fwd<3, 2, true, 43, 2>(lw + 7 * WSLOT, B, Z, g, lr);
    B = layer_fwd<3, 2, true, 43, 2>(lw + 8 * WSLOT, B, Z, g, lr);

    // ---- layer 9: linear, store fp32 via base + immediate offsets ----
    {
      const _Float16* p = lw + 9 * WSLOT + lr * WSTRIDE + 8 * g;
      f32x4 a9[3];
      a9[0] = __builtin_amdgcn_mfma_f32_16x16x32_f16(*(const f16x8*)(p),
                                                     B.c0, Z, 0, 0, 0);
      a9[1] = __builtin_amdgcn_mfma_f32_16x16x32_f16(
          *(const f16x8*)(p + 16 * WSTRIDE), B.c0, Z, 0, 0, 0);
      a9[2] = __builtin_amdgcn_mfma_f32_16x16x32_f16(
          *(const f16x8*)(p + 32 * WSTRIDE), B.c0, Z, 0, 0, 0);
      a9[0] = __builtin_amdgcn_mfma_f32_16x16x32_f16(*(const f16x8*)(p + 32),
                                                     B.c1, a9[0], 0, 0, 0);
      a9[1] = __builtin_amdgcn_mfma_f32_16x16x32_f16(
          *(const f16x8*)(p + 16 * WSTRIDE + 32), B.c1, a9[1], 0, 0, 0);
      a9[2] = __builtin_amdgcn_mfma_f32_16x16x32_f16(
          *(const f16x8*)(p + 32 * WSTRIDE + 32), B.c1, a9[2], 0, 0, 0);

      char* ob = (char*)out + ((size_t)(row0 + lr) * ROWB + 16u * g);
#pragma unroll
      for (int t = 0; t < 3; ++t)
#pragma unroll
        for (int r = 0; r < 4; ++r) {
          // col = 16t + 4g + r < 43; t<2 always in range
          if (t < 2 || 4 * g + r < 11)
            *(float*)(ob + 64 * t + 4 * r) = a9[t][r];
        }
    }
  }
}

extern "C" void kernel_launch(void* const* d_in, const int* in_sizes, int n_in,
                              void* d_out, int out_size, void* d_ws,
                              size_t ws_size, hipStream_t stream) {
  const float* x = (const float*)d_in[0];
  const float* W[10];
  const float* B[10];
  for (int i = 0; i < 10; ++i) {
    W[i] = (const float*)d_in[1 + 2 * i];
    B[i] = (const float*)d_in[2 + 2 * i];
  }
  (void)hipFuncSetAttribute(reinterpret_cast<const void*>(ae_kernel),
                            hipFuncAttributeMaxDynamicSharedMemorySize,
                            SMEM_BYTES);
  ae_kernel<<<dim3(NBLK), dim3(TPB), SMEM_BYTES, stream>>>(
      x, W[0], B[0], W[1], B[1], W[2], B[2], W[3], B[3], W[4], B[4],
      W[5], B[5], W[6], B[6], W[7], B[7], W[8], B[8], W[9], B[9],
      (float*)d_out);
}

// Round 14
// 410.044 us; speedup vs baseline: 1.8953x; 1.0064x over previous
//
#include <hip/hip_runtime.h>

// SensorAutoEncoder: 10-layer MLP over 1M rows of 43 floats. fp16 MFMA
// (16x16x32) + fp32 accumulate. R14 = R13 (LDS = weights only, 64,000 B ->
// 2 blocks/CU; M=16/wave; register-resident F-permuted layer chain; fast-path
// x loads with last-block clamp) + __launch_bounds__(TPB, 4): gives the
// allocator a 128-VGPR budget (min-waves guarantee, NOT an occupancy cap) so
// the natural ~50-VGPR allocation fits with ZERO scratch, while LDS/threads
// still admit 2 blocks/CU = 8 waves/SIMD. R12/R13's plain (TPB) defaulted to
// a 64-VGPR target and spilled ~1 GB of scratch traffic per dispatch.
//   B slot (c,g,j): c==0 -> F = 16*(j>>2) + 4g + (j&3)
//                   c==1, j<4 -> F = 32 + 4g + j ; else zero pad
// bias via k==KL row; forced 1.0 multiplier at slot (c1,g=1,j=3).

typedef __fp16 pk16x2 __attribute__((ext_vector_type(2)));   // cvt_pkrtz type
typedef _Float16 f16x8 __attribute__((ext_vector_type(8)));
typedef float f32x4 __attribute__((ext_vector_type(4)));
typedef unsigned u32x4 __attribute__((ext_vector_type(4)));

#define TPB 1024
#define NBLK 512
#define ITERS 8
#define NROWS 1048576
#define NCOL 43
#define ROWB 172u                        // bytes per x / out row (43 f32)
#define XBYTES ((size_t)NROWS * ROWB)    // 180,355,072
#define WSTRIDE 72                       // halfwords per W^T row (144 B)
#define SLOT_ROWS 44
#define WSLOT (SLOT_ROWS * WSTRIDE)      // 3168 halfwords per layer slot
#define W_HW (10 * WSLOT)                // 31680 halfwords
#define W_PAD_HW 320                     // layer-9 overhang rows, zeroed
#define SMEM_BYTES ((W_HW + W_PAD_HW) * 2)  // 64000 B -> 2 blocks/CU

__device__ __forceinline__ float fast_tanh(float x) {
  // tanh(x) = 1 - 2/(1 + e^{2x});  e^{2x} = 2^{x * 2*log2(e)}
  float t = __builtin_amdgcn_exp2f(x * 2.8853900817779268f);
  float r = __builtin_amdgcn_rcpf(t + 1.0f);
  return __builtin_fmaf(-2.0f, r, 1.0f);
}

__device__ __forceinline__ unsigned pk2(float a, float b) {
  pk16x2 h = __builtin_amdgcn_cvt_pkrtz(a, b);
  return __builtin_bit_cast(unsigned, h);
}

struct Frag2 { f16x8 c0, c1; };

// Build the layer-0 B-frag for row (rb = row*172 + 32g bytes into x).
// CLAMP=false: single base pointer + immediate offsets (2 addr VGPRs).
// CLAMP=true (last block only): per-element clamp to the buffer end.
template <bool CLAMP>
__device__ __forceinline__ Frag2 build_b0(const char* __restrict__ xc,
                                          unsigned rb, int g) {
  f32x4 q0, q1, q2, q3;
  if constexpr (CLAMP) {
    const unsigned LIM = (unsigned)(XBYTES - 4);
#pragma unroll
    for (int j = 0; j < 4; ++j) {
      q0[j] = *(const float*)(xc + (rb + 4u * j));
      q1[j] = *(const float*)(xc + (rb + 16u + 4u * j));
      unsigned a2 = rb + 128u + 4u * j;
      unsigned a3 = rb + 144u + 4u * j;
      q2[j] = *(const float*)(xc + (a2 < LIM ? a2 : LIM));
      q3[j] = *(const float*)(xc + (a3 < LIM ? a3 : LIM));
    }
  } else {
    const char* p = xc + rb;
#pragma unroll
    for (int j = 0; j < 4; ++j) {
      q0[j] = *(const float*)(p + 4 * j);
      q1[j] = *(const float*)(p + 16 + 4 * j);
      q2[j] = *(const float*)(p + 128 + 4 * j);   // rows < N-1: overrun <=80B
      q3[j] = *(const float*)(p + 144 + 4 * j);   // stays in-buffer; junk ok
    }
  }
  float e3 = (g == 1) ? 1.0f : q2[3];   // k==43 bias multiplier := 1.0
  u32x4 d0 = {pk2(q0[0], q0[1]), pk2(q0[2], q0[3]),
              pk2(q1[0], q1[1]), pk2(q1[2], q1[3])};
  u32x4 d1 = {pk2(q2[0], q2[1]), pk2(q2[2], e3),
              pk2(q3[0], q3[1]), pk2(q3[2], q3[3])};
  Frag2 B;
  B.c0 = __builtin_bit_cast(f16x8, d0);
  B.c1 = __builtin_bit_cast(f16x8, d1);
  return B;
}

// One layer: JIT A-reads from LDS weights, MFMA (zero-C first chunk),
// epilogue (tanh + bias-column 1.0 forcing), pack into next B-frag.
template <int NT, int KC, bool DOTANH, int NLOUT, int KCN>
__device__ __forceinline__ Frag2 layer_fwd(const _Float16* __restrict__ Wl,
                                           Frag2 Bi, f32x4 Z, int g, int lr) {
  const _Float16* p = Wl + lr * WSTRIDE + 8 * g;
  f32x4 acc[3];
  acc[0] = __builtin_amdgcn_mfma_f32_16x16x32_f16(*(const f16x8*)(p),
                                                  Bi.c0, Z, 0, 0, 0);
  if constexpr (NT > 1)
    acc[1] = __builtin_amdgcn_mfma_f32_16x16x32_f16(
        *(const f16x8*)(p + 16 * WSTRIDE), Bi.c0, Z, 0, 0, 0);
  if constexpr (NT > 2)
    acc[2] = __builtin_amdgcn_mfma_f32_16x16x32_f16(
        *(const f16x8*)(p + 32 * WSTRIDE), Bi.c0, Z, 0, 0, 0);
  if constexpr (KC > 1) {
    acc[0] = __builtin_amdgcn_mfma_f32_16x16x32_f16(*(const f16x8*)(p + 32),
                                                    Bi.c1, acc[0], 0, 0, 0);
    if constexpr (NT > 1)
      acc[1] = __builtin_amdgcn_mfma_f32_16x16x32_f16(
          *(const f16x8*)(p + 16 * WSTRIDE + 32), Bi.c1, acc[1], 0, 0, 0);
    if constexpr (NT > 2)
      acc[2] = __builtin_amdgcn_mfma_f32_16x16x32_f16(
          *(const f16x8*)(p + 32 * WSTRIDE + 32), Bi.c1, acc[2], 0, 0, 0);
  }

  unsigned pk[3][2];
#pragma unroll
  for (int t = 0; t < NT; ++t) {
    float v[4];
#pragma unroll
    for (int r = 0; r < 4; ++r) {
      float u = acc[t][r];
      if (DOTANH) u = fast_tanh(u);
      if (t == (NLOUT >> 4)) {                 // bias-mult column -> 1.0
        int col = 16 * t + 4 * g + r;
        u = (col == NLOUT) ? 1.0f : u;
      }
      v[r] = u;
    }
    pk[t][0] = pk2(v[0], v[1]);
    pk[t][1] = pk2(v[2], v[3]);
  }
  Frag2 O;
  u32x4 d0 = {pk[0][0], pk[0][1], pk[1][0], pk[1][1]};
  O.c0 = __builtin_bit_cast(f16x8, d0);
  if (KCN == 2) {
    u32x4 d1 = {pk[NT - 1][0], pk[NT - 1][1], 0u, 0u};
    O.c1 = __builtin_bit_cast(f16x8, d1);
  } else {
    O.c1 = O.c0;   // unused by a KC=1 consumer
  }
  return O;
}

extern "C" __global__ void __launch_bounds__(TPB, 4)
ae_kernel(const float* __restrict__ x,
          const float* __restrict__ W0, const float* __restrict__ B0,
          const float* __restrict__ W1, const float* __restrict__ B1,
          const float* __restrict__ W2, const float* __restrict__ B2,
          const float* __restrict__ W3, const float* __restrict__ B3,
          const float* __restrict__ W4, const float* __restrict__ B4,
          const float* __restrict__ W5, const float* __restrict__ B5,
          const float* __restrict__ W6, const float* __restrict__ B6,
          const float* __restrict__ W7, const float* __restrict__ B7,
          const float* __restrict__ W8, const float* __restrict__ B8,
          const float* __restrict__ W9, const float* __restrict__ B9,
          float* __restrict__ out) {
  extern __shared__ char smem[];
  _Float16* lw = (_Float16*)smem;

  const int tid = threadIdx.x;
  const int wave = tid >> 6;
  const int lane = tid & 63;
  const int g = lane >> 4;
  const int lr = lane & 15;

  // ---- stage weights as fp16 W^T (k-permutation F for layers 1..9), bias
  //      at the slot mapping to k==KL; 44 rows per slot; zero the pad ----
  {
    const float* Wp[10] = {W0, W1, W2, W3, W4, W5, W6, W7, W8, W9};
    const float* Bp[10] = {B0, B1, B2, B3, B4, B5, B6, B7, B8, B9};
    const int KLs[10] = {43, 43, 43, 43, 43, 21, 43, 43, 43, 43};
    const int NLs[10] = {43, 43, 43, 43, 21, 43, 43, 43, 43, 43};
#pragma unroll
    for (int L = 0; L < 10; ++L) {
      const float* Wl = Wp[L];
      const float* Bl = Bp[L];
      const int KL = KLs[L], NL = NLs[L];
      for (int idx = tid; idx < SLOT_ROWS * 64; idx += TPB) {
        int n = idx >> 6, kp = idx & 63;
        float v = 0.0f;
        if (n < NL) {
          int c = kp >> 5, g2 = (kp >> 3) & 3, j = kp & 7;
          int F;
          if (L == 0) F = kp;                               // natural
          else if (c == 0) F = 16 * (j >> 2) + 4 * g2 + (j & 3);
          else if (j < 4)  F = 32 + 4 * g2 + j;             // t=2 half
          else             F = 63;                          // zero pad slot
          if (F < KL) v = Wl[F * NL + n];                   // W^T: W[F][n]
          else if (F == KL) v = Bl[n];                      // bias row
        }
        lw[L * WSLOT + n * WSTRIDE + kp] = (_Float16)v;
      }
    }
    if (tid < W_PAD_HW) lw[W_HW + tid] = (_Float16)0.0f;
  }

  __syncthreads();  // weights ready; only barrier in the kernel

  const char* xc = (const char*)x;
  const unsigned blockbase = (unsigned)blockIdx.x * (ITERS * 256) + wave * 16;
  const bool lastblk = (blockIdx.x == NBLK - 1);
  const f32x4 Z = {0.f, 0.f, 0.f, 0.f};   // shared MFMA C-init block

#pragma unroll 1
  for (int it = 0; it < ITERS; ++it) {
    const unsigned row0 = blockbase + (unsigned)it * 256u;
    const unsigned rb = (row0 + lr) * ROWB + 32u * g;

    // ---- layer-0 B-frag (fast path except the last block) ----
    Frag2 B = lastblk ? build_b0<true>(xc, rb, g)
                      : build_b0<false>(xc, rb, g);

    // ---- layers 0..8, hidden state entirely in registers ----
    B = layer_fwd<3, 2, true, 43, 2>(lw + 0 * WSLOT, B, Z, g, lr);
    B = layer_fwd<3, 2, true, 43, 2>(lw + 1 * WSLOT, B, Z, g, lr);
    B = layer_fwd<3, 2, true, 43, 2>(lw + 2 * WSLOT, B, Z, g, lr);
    B = layer_fwd<3, 2, true, 43, 2>(lw + 3 * WSLOT, B, Z, g, lr);
    B = layer_fwd<2, 2, false, 21, 1>(lw + 4 * WSLOT, B, Z, g, lr);
    B = layer_fwd<3, 1, true, 43, 2>(lw + 5 * WSLOT, B, Z, g, lr);
    B = layer_fwd<3, 2, true, 43, 2>(lw + 6 * WSLOT, B, Z, g, lr);
    B = layer_fwd<3, 2, true, 43, 2>(lw + 7 * WSLOT, B, Z, g, lr);
    B = layer_fwd<3, 2, true, 43, 2>(lw + 8 * WSLOT, B, Z, g, lr);

    // ---- layer 9: linear, store fp32 via base + immediate offsets ----
    {
      const _Float16* p = lw + 9 * WSLOT + lr * WSTRIDE + 8 * g;
      f32x4 a9[3];
      a9[0] = __builtin_amdgcn_mfma_f32_16x16x32_f16(*(const f16x8*)(p),
                                                     B.c0, Z, 0, 0, 0);
      a9[1] = __builtin_amdgcn_mfma_f32_16x16x32_f16(
          *(const f16x8*)(p + 16 * WSTRIDE), B.c0, Z, 0, 0, 0);
      a9[2] = __builtin_amdgcn_mfma_f32_16x16x32_f16(
          *(const f16x8*)(p + 32 * WSTRIDE), B.c0, Z, 0, 0, 0);
      a9[0] = __builtin_amdgcn_mfma_f32_16x16x32_f16(*(const f16x8*)(p + 32),
                                                     B.c1, a9[0], 0, 0, 0);
      a9[1] = __builtin_amdgcn_mfma_f32_16x16x32_f16(
          *(const f16x8*)(p + 16 * WSTRIDE + 32), B.c1, a9[1], 0, 0, 0);
      a9[2] = __builtin_amdgcn_mfma_f32_16x16x32_f16(
          *(const f16x8*)(p + 32 * WSTRIDE + 32), B.c1, a9[2], 0, 0, 0);

      char* ob = (char*)out + ((size_t)(row0 + lr) * ROWB + 16u * g);
#pragma unroll
      for (int t = 0; t < 3; ++t)
#pragma unroll
        for (int r = 0; r < 4; ++r) {
          // col = 16t + 4g + r < 43; t<2 always in range
          if (t < 2 || 4 * g + r < 11)
            *(float*)(ob + 64 * t + 4 * r) = a9[t][r];
        }
    }
  }
}

extern "C" void kernel_launch(void* const* d_in, const int* in_sizes, int n_in,
                              void* d_out, int out_size, void* d_ws,
                              size_t ws_size, hipStream_t stream) {
  const float* x = (const float*)d_in[0];
  const float* W[10];
  const float* B[10];
  for (int i = 0; i < 10; ++i) {
    W[i] = (const float*)d_in[1 + 2 * i];
    B[i] = (const float*)d_in[2 + 2 * i];
  }
  (void)hipFuncSetAttribute(reinterpret_cast<const void*>(ae_kernel),
                            hipFuncAttributeMaxDynamicSharedMemorySize,
                            SMEM_BYTES);
  ae_kernel<<<dim3(NBLK), dim3(TPB), SMEM_BYTES, stream>>>(
      x, W[0], B[0], W[1], B[1], W[2], B[2], W[3], B[3], W[4], B[4],
      W[5], B[5], W[6], B[6], W[7], B[7], W[8], B[8], W[9], B[9],
      (float*)d_out);
}